// Round 1
// baseline (426.908 us; speedup 1.0000x reference)
//
#include <hip/hip_runtime.h>
#include <hip/hip_bf16.h>
#include <cstdint>
#include <cstddef>

typedef __attribute__((ext_vector_type(8))) short bf16x8;   // 8 bf16 in 4 VGPRs
typedef __attribute__((ext_vector_type(4))) float f32x4;

static __device__ __forceinline__ unsigned short f2bf(float f) {
    union { float f; unsigned int u; } x; x.f = f;
    unsigned int u = x.u;
    unsigned int r = (u + 0x7FFFu + ((u >> 16) & 1u)) >> 16;  // RNE
    return (unsigned short)r;
}

static __device__ __forceinline__ f32x4 mfma_bf16(bf16x8 a, bf16x8 b, f32x4 c) {
    return __builtin_amdgcn_mfma_f32_16x16x32_bf16(a, b, c, 0, 0, 0);
}

// ---------------------------------------------------------------------------
// Attention: one block per (window b, head h). 4 waves, wave w owns rows
// 16w..16w+15 of the 64x64 score tile. Writes fp32 attention output to xout.
// ---------------------------------------------------------------------------
__global__ __launch_bounds__(256) void attn_kernel(
    const float* __restrict__ q, const float* __restrict__ k,
    const float* __restrict__ v, const float* __restrict__ mask,
    float* __restrict__ xout)
{
    __shared__ unsigned short Qs[64][40];   // 64x32 bf16, padded
    __shared__ unsigned short Ks[64][40];
    __shared__ unsigned short Vt[32][72];   // V transposed: Vt[d][n]
    __shared__ unsigned short Ps[64][72];   // P bf16 (row-major, padded)

    const int tid  = threadIdx.x;
    const int b    = blockIdx.x >> 3;
    const int h    = blockIdx.x & 7;
    const int lane = tid & 63;
    const int l15  = lane & 15;
    const int g    = lane >> 4;
    const int w    = tid >> 6;

    // ---- stage Q,K,V head slice (64x32 fp32 -> bf16) ----
    {
        int row = tid >> 2;
        int seg = tid & 3;                  // 8 floats per thread
        size_t base = ((size_t)(b * 64 + row)) * 256 + h * 32 + seg * 8;

        float4 a0 = *(const float4*)(q + base);
        float4 a1 = *(const float4*)(q + base + 4);
        unsigned short* p = &Qs[row][seg * 8];
        p[0]=f2bf(a0.x); p[1]=f2bf(a0.y); p[2]=f2bf(a0.z); p[3]=f2bf(a0.w);
        p[4]=f2bf(a1.x); p[5]=f2bf(a1.y); p[6]=f2bf(a1.z); p[7]=f2bf(a1.w);

        a0 = *(const float4*)(k + base);
        a1 = *(const float4*)(k + base + 4);
        p = &Ks[row][seg * 8];
        p[0]=f2bf(a0.x); p[1]=f2bf(a0.y); p[2]=f2bf(a0.z); p[3]=f2bf(a0.w);
        p[4]=f2bf(a1.x); p[5]=f2bf(a1.y); p[6]=f2bf(a1.z); p[7]=f2bf(a1.w);

        a0 = *(const float4*)(v + base);
        a1 = *(const float4*)(v + base + 4);
        int c = seg * 8;
        Vt[c + 0][row] = f2bf(a0.x);
        Vt[c + 1][row] = f2bf(a0.y);
        Vt[c + 2][row] = f2bf(a0.z);
        Vt[c + 3][row] = f2bf(a0.w);
        Vt[c + 4][row] = f2bf(a1.x);
        Vt[c + 5][row] = f2bf(a1.y);
        Vt[c + 6][row] = f2bf(a1.z);
        Vt[c + 7][row] = f2bf(a1.w);
    }
    __syncthreads();

    // ---- S = Q K^T  (wave w: rows 16w..16w+15, 4 column tiles) ----
    f32x4 s[4];
    {
        bf16x8 aQ = *(const bf16x8*)&Qs[w * 16 + l15][g * 8];
        #pragma unroll
        for (int ct = 0; ct < 4; ++ct) {
            bf16x8 bK = *(const bf16x8*)&Ks[ct * 16 + l15][g * 8];
            f32x4 z = {0.f, 0.f, 0.f, 0.f};
            s[ct] = mfma_bf16(aQ, bK, z);
        }
    }

    // ---- (S + mask) * 1/sqrt(32), row softmax (deferred normalization) ----
    const float* mbase = mask + (size_t)(b & 63) * 4096;
    const float INV = 0.17677669529663688f;
    float rsum[4];
    #pragma unroll
    for (int r = 0; r < 4; ++r) {
        int row = w * 16 + g * 4 + r;
        float pr[4];
        #pragma unroll
        for (int ct = 0; ct < 4; ++ct)
            pr[ct] = (s[ct][r] + mbase[row * 64 + ct * 16 + l15]) * INV;
        float m = fmaxf(fmaxf(pr[0], pr[1]), fmaxf(pr[2], pr[3]));
        #pragma unroll
        for (int off = 1; off < 16; off <<= 1)
            m = fmaxf(m, __shfl_xor(m, off));
        float sum = 0.f;
        #pragma unroll
        for (int ct = 0; ct < 4; ++ct) { pr[ct] = __expf(pr[ct] - m); sum += pr[ct]; }
        #pragma unroll
        for (int off = 1; off < 16; off <<= 1)
            sum += __shfl_xor(sum, off);
        rsum[r] = sum;
        #pragma unroll
        for (int ct = 0; ct < 4; ++ct)
            Ps[row][ct * 16 + l15] = f2bf(pr[ct]);
    }
    // P rows are wave-private: no __syncthreads needed (compiler emits lgkmcnt).

    // ---- O = P V ----
    f32x4 o[2] = {};
    #pragma unroll
    for (int ks = 0; ks < 2; ++ks) {
        bf16x8 pa = *(const bf16x8*)&Ps[w * 16 + l15][ks * 32 + g * 8];
        #pragma unroll
        for (int n = 0; n < 2; ++n) {
            bf16x8 vb = *(const bf16x8*)&Vt[n * 16 + l15][ks * 32 + g * 8];
            o[n] = mfma_bf16(pa, vb, o[n]);
        }
    }

    // ---- write fp32 attention output (normalized) ----
    #pragma unroll
    for (int n = 0; n < 2; ++n) {
        #pragma unroll
        for (int r = 0; r < 4; ++r) {
            int row = w * 16 + g * 4 + r;
            xout[((size_t)(b * 64 + row)) * 256 + h * 32 + n * 16 + l15] =
                o[n][r] / rsum[r];
        }
    }
}

// ---------------------------------------------------------------------------
// GEMM1: h = gelu(x @ w1 + b1), x fp32 (lda=256), w1 fp32 (256x1024), h bf16.
// 128x128 tile, BK=64, 4 waves in 2x2.
// ---------------------------------------------------------------------------
__global__ __launch_bounds__(256) void mlp_gemm1(
    const float* __restrict__ x, const float* __restrict__ w1,
    const float* __restrict__ b1, unsigned short* __restrict__ hbuf)
{
    __shared__ unsigned short As[128][72];
    __shared__ unsigned short Bs[128][72];   // Bs[n][k]

    const int tid = threadIdx.x;
    const int bn = blockIdx.x;               // 0..7
    const int bm = blockIdx.y;
    const int lane = tid & 63;
    const int l15 = lane & 15;
    const int g = lane >> 4;
    const int wid = tid >> 6;
    const int wm = wid >> 1, wn = wid & 1;

    f32x4 acc[4][4] = {};

    for (int k0 = 0; k0 < 256; k0 += 64) {
        // stage A (128x64 fp32 -> bf16), coalesced float4
        #pragma unroll
        for (int i = 0; i < 8; ++i) {
            int f = tid + 256 * i;
            int row = f >> 4, c = (f & 15) * 4;
            float4 d = *(const float4*)(x + (size_t)(bm * 128 + row) * 256 + k0 + c);
            unsigned short* p = &As[row][c];
            p[0]=f2bf(d.x); p[1]=f2bf(d.y); p[2]=f2bf(d.z); p[3]=f2bf(d.w);
        }
        // stage B (64x128 fp32 -> bf16, transposed into Bs[n][k])
        #pragma unroll
        for (int i = 0; i < 8; ++i) {
            int f = tid + 256 * i;
            int row = f >> 5, c = (f & 31) * 4;
            float4 d = *(const float4*)(w1 + (size_t)(k0 + row) * 1024 + bn * 128 + c);
            Bs[c + 0][row] = f2bf(d.x);
            Bs[c + 1][row] = f2bf(d.y);
            Bs[c + 2][row] = f2bf(d.z);
            Bs[c + 3][row] = f2bf(d.w);
        }
        __syncthreads();
        #pragma unroll
        for (int ks = 0; ks < 2; ++ks) {
            bf16x8 aF[4], bF[4];
            #pragma unroll
            for (int t = 0; t < 4; ++t)
                aF[t] = *(const bf16x8*)&As[wm * 64 + t * 16 + l15][ks * 32 + g * 8];
            #pragma unroll
            for (int t = 0; t < 4; ++t)
                bF[t] = *(const bf16x8*)&Bs[wn * 64 + t * 16 + l15][ks * 32 + g * 8];
            #pragma unroll
            for (int mt = 0; mt < 4; ++mt)
                #pragma unroll
                for (int nt = 0; nt < 4; ++nt)
                    acc[mt][nt] = mfma_bf16(aF[mt], bF[nt], acc[mt][nt]);
        }
        __syncthreads();
    }

    #pragma unroll
    for (int mt = 0; mt < 4; ++mt) {
        #pragma unroll
        for (int nt = 0; nt < 4; ++nt) {
            int col = bn * 128 + wn * 64 + nt * 16 + l15;
            float bias = b1[col];
            #pragma unroll
            for (int r = 0; r < 4; ++r) {
                int row = bm * 128 + wm * 64 + mt * 16 + g * 4 + r;
                float val = acc[mt][nt][r] + bias;
                val = 0.5f * val * (1.0f + erff(val * 0.70710678118654752f));
                hbuf[(size_t)row * 1024 + col] = f2bf(val);
            }
        }
    }
}

// ---------------------------------------------------------------------------
// GEMM2: out = resid + h @ w2 + b2. h bf16 (lda=1024), w2 fp32 (1024x256),
// resid/out fp32 in the same buffer (each element read+written by one thread).
// ---------------------------------------------------------------------------
__global__ __launch_bounds__(256) void mlp_gemm2(
    const unsigned short* __restrict__ hbuf, const float* __restrict__ w2,
    const float* __restrict__ b2, float* __restrict__ xo)
{
    __shared__ unsigned short As[128][72];
    __shared__ unsigned short Bs[128][72];

    const int tid = threadIdx.x;
    const int bn = blockIdx.x;               // 0..1
    const int bm = blockIdx.y;
    const int lane = tid & 63;
    const int l15 = lane & 15;
    const int g = lane >> 4;
    const int wid = tid >> 6;
    const int wm = wid >> 1, wn = wid & 1;

    f32x4 acc[4][4] = {};

    for (int k0 = 0; k0 < 1024; k0 += 64) {
        // stage A (128x64 bf16, direct 16B copies)
        #pragma unroll
        for (int i = 0; i < 4; ++i) {
            int f = tid + 256 * i;
            int row = f >> 3, seg = (f & 7) * 8;
            bf16x8 d = *(const bf16x8*)(hbuf + (size_t)(bm * 128 + row) * 1024 + k0 + seg);
            *(bf16x8*)&As[row][seg] = d;
        }
        // stage B (64x128 fp32 -> bf16, transposed)
        #pragma unroll
        for (int i = 0; i < 8; ++i) {
            int f = tid + 256 * i;
            int row = f >> 5, c = (f & 31) * 4;
            float4 d = *(const float4*)(w2 + (size_t)(k0 + row) * 256 + bn * 128 + c);
            Bs[c + 0][row] = f2bf(d.x);
            Bs[c + 1][row] = f2bf(d.y);
            Bs[c + 2][row] = f2bf(d.z);
            Bs[c + 3][row] = f2bf(d.w);
        }
        __syncthreads();
        #pragma unroll
        for (int ks = 0; ks < 2; ++ks) {
            bf16x8 aF[4], bF[4];
            #pragma unroll
            for (int t = 0; t < 4; ++t)
                aF[t] = *(const bf16x8*)&As[wm * 64 + t * 16 + l15][ks * 32 + g * 8];
            #pragma unroll
            for (int t = 0; t < 4; ++t)
                bF[t] = *(const bf16x8*)&Bs[wn * 64 + t * 16 + l15][ks * 32 + g * 8];
            #pragma unroll
            for (int mt = 0; mt < 4; ++mt)
                #pragma unroll
                for (int nt = 0; nt < 4; ++nt)
                    acc[mt][nt] = mfma_bf16(aF[mt], bF[nt], acc[mt][nt]);
        }
        __syncthreads();
    }

    #pragma unroll
    for (int mt = 0; mt < 4; ++mt) {
        #pragma unroll
        for (int nt = 0; nt < 4; ++nt) {
            int col = bn * 128 + wn * 64 + nt * 16 + l15;
            float bias = b2[col];
            #pragma unroll
            for (int r = 0; r < 4; ++r) {
                int row = bm * 128 + wm * 64 + mt * 16 + g * 4 + r;
                size_t idx = (size_t)row * 256 + col;
                xo[idx] = acc[mt][nt][r] + bias + xo[idx];
            }
        }
    }
}

// ---------------------------------------------------------------------------
extern "C" void kernel_launch(void* const* d_in, const int* in_sizes, int n_in,
                              void* d_out, int out_size, void* d_ws, size_t ws_size,
                              hipStream_t stream)
{
    const float* q    = (const float*)d_in[0];
    const float* k    = (const float*)d_in[1];
    const float* v    = (const float*)d_in[2];
    const float* mask = (const float*)d_in[3];
    const float* w1   = (const float*)d_in[6];
    const float* b1   = (const float*)d_in[7];
    const float* w2   = (const float*)d_in[8];
    const float* b2   = (const float*)d_in[9];

    float* xout = (float*)d_out;                       // attention out == residual == final out
    unsigned short* hbuf = (unsigned short*)d_ws;      // bf16 hidden chunk

    attn_kernel<<<8192, 256, 0, stream>>>(q, k, v, mask, xout);

    const int M = 65536;
    const size_t h_full = (size_t)M * 1024 * 2;
    int chunk = M;
    if (ws_size < h_full) {
        size_t c = (ws_size / 2048) & ~(size_t)127;    // rows that fit, multiple of 128
        chunk = (c < 128) ? 128 : (int)((c > (size_t)M) ? M : c);
    }

    for (int m0 = 0; m0 < M; m0 += chunk) {
        int rows = (M - m0 < chunk) ? (M - m0) : chunk;
        dim3 g1(8, rows / 128);
        mlp_gemm1<<<g1, 256, 0, stream>>>(xout + (size_t)m0 * 256, w1, b1, hbuf);
        dim3 g2(2, rows / 128);
        mlp_gemm2<<<g2, 256, 0, stream>>>(hbuf, w2, b2, xout + (size_t)m0 * 256);
    }
}

// Round 2
// 298.470 us; speedup vs baseline: 1.4303x; 1.4303x over previous
//
#include <hip/hip_runtime.h>
#include <hip/hip_bf16.h>
#include <cstdint>
#include <cstddef>

typedef __attribute__((ext_vector_type(8))) short bf16x8;   // 8 bf16 in 4 VGPRs
typedef __attribute__((ext_vector_type(4))) float f32x4;

static __device__ __forceinline__ unsigned short f2bf(float f) {
    union { float f; unsigned int u; } x; x.f = f;
    unsigned int u = x.u;
    unsigned int r = (u + 0x7FFFu + ((u >> 16) & 1u)) >> 16;  // RNE
    return (unsigned short)r;
}

static __device__ __forceinline__ f32x4 mfma_bf16(bf16x8 a, bf16x8 b, f32x4 c) {
    return __builtin_amdgcn_mfma_f32_16x16x32_bf16(a, b, c, 0, 0, 0);
}

static __device__ __forceinline__ bf16x8 pack8(float4 a, float4 b) {
    bf16x8 f;
    f[0]=(short)f2bf(a.x); f[1]=(short)f2bf(a.y); f[2]=(short)f2bf(a.z); f[3]=(short)f2bf(a.w);
    f[4]=(short)f2bf(b.x); f[5]=(short)f2bf(b.y); f[6]=(short)f2bf(b.z); f[7]=(short)f2bf(b.w);
    return f;
}

// ---------------------------------------------------------------------------
// Attention: one block per (window b, head h). 4 waves, wave w owns rows
// 16w..16w+15 of the 64x64 score tile. Writes fp32 attention output to xout.
// ---------------------------------------------------------------------------
__global__ __launch_bounds__(256) void attn_kernel(
    const float* __restrict__ q, const float* __restrict__ k,
    const float* __restrict__ v, const float* __restrict__ mask,
    float* __restrict__ xout)
{
    __shared__ unsigned short Qs[64][40];   // 64x32 bf16, padded
    __shared__ unsigned short Ks[64][40];
    __shared__ unsigned short Vt[32][72];   // V transposed: Vt[d][n]
    __shared__ unsigned short Ps[64][72];   // P bf16 (row-major, padded)

    const int tid  = threadIdx.x;
    const int b    = blockIdx.x >> 3;
    const int h    = blockIdx.x & 7;
    const int lane = tid & 63;
    const int l15  = lane & 15;
    const int g    = lane >> 4;
    const int w    = tid >> 6;

    {
        int row = tid >> 2;
        int seg = tid & 3;                  // 8 floats per thread
        size_t base = ((size_t)(b * 64 + row)) * 256 + h * 32 + seg * 8;

        float4 a0 = *(const float4*)(q + base);
        float4 a1 = *(const float4*)(q + base + 4);
        unsigned short* p = &Qs[row][seg * 8];
        p[0]=f2bf(a0.x); p[1]=f2bf(a0.y); p[2]=f2bf(a0.z); p[3]=f2bf(a0.w);
        p[4]=f2bf(a1.x); p[5]=f2bf(a1.y); p[6]=f2bf(a1.z); p[7]=f2bf(a1.w);

        a0 = *(const float4*)(k + base);
        a1 = *(const float4*)(k + base + 4);
        p = &Ks[row][seg * 8];
        p[0]=f2bf(a0.x); p[1]=f2bf(a0.y); p[2]=f2bf(a0.z); p[3]=f2bf(a0.w);
        p[4]=f2bf(a1.x); p[5]=f2bf(a1.y); p[6]=f2bf(a1.z); p[7]=f2bf(a1.w);

        a0 = *(const float4*)(v + base);
        a1 = *(const float4*)(v + base + 4);
        int c = seg * 8;
        Vt[c + 0][row] = f2bf(a0.x);
        Vt[c + 1][row] = f2bf(a0.y);
        Vt[c + 2][row] = f2bf(a0.z);
        Vt[c + 3][row] = f2bf(a0.w);
        Vt[c + 4][row] = f2bf(a1.x);
        Vt[c + 5][row] = f2bf(a1.y);
        Vt[c + 6][row] = f2bf(a1.z);
        Vt[c + 7][row] = f2bf(a1.w);
    }
    __syncthreads();

    // ---- S = Q K^T ----
    f32x4 s[4];
    {
        bf16x8 aQ = *(const bf16x8*)&Qs[w * 16 + l15][g * 8];
        #pragma unroll
        for (int ct = 0; ct < 4; ++ct) {
            bf16x8 bK = *(const bf16x8*)&Ks[ct * 16 + l15][g * 8];
            f32x4 z = {0.f, 0.f, 0.f, 0.f};
            s[ct] = mfma_bf16(aQ, bK, z);
        }
    }

    // ---- (S + mask) * 1/sqrt(32), row softmax ----
    const float* mbase = mask + (size_t)(b & 63) * 4096;
    const float INV = 0.17677669529663688f;
    float rsum[4];
    #pragma unroll
    for (int r = 0; r < 4; ++r) {
        int row = w * 16 + g * 4 + r;
        float pr[4];
        #pragma unroll
        for (int ct = 0; ct < 4; ++ct)
            pr[ct] = (s[ct][r] + mbase[row * 64 + ct * 16 + l15]) * INV;
        float m = fmaxf(fmaxf(pr[0], pr[1]), fmaxf(pr[2], pr[3]));
        #pragma unroll
        for (int off = 1; off < 16; off <<= 1)
            m = fmaxf(m, __shfl_xor(m, off));
        float sum = 0.f;
        #pragma unroll
        for (int ct = 0; ct < 4; ++ct) { pr[ct] = __expf(pr[ct] - m); sum += pr[ct]; }
        #pragma unroll
        for (int off = 1; off < 16; off <<= 1)
            sum += __shfl_xor(sum, off);
        rsum[r] = sum;
        #pragma unroll
        for (int ct = 0; ct < 4; ++ct)
            Ps[row][ct * 16 + l15] = f2bf(pr[ct]);
    }

    // ---- O = P V ----
    f32x4 o[2] = {};
    #pragma unroll
    for (int ks = 0; ks < 2; ++ks) {
        bf16x8 pa = *(const bf16x8*)&Ps[w * 16 + l15][ks * 32 + g * 8];
        #pragma unroll
        for (int n = 0; n < 2; ++n) {
            bf16x8 vb = *(const bf16x8*)&Vt[n * 16 + l15][ks * 32 + g * 8];
            o[n] = mfma_bf16(pa, vb, o[n]);
        }
    }

    #pragma unroll
    for (int n = 0; n < 2; ++n) {
        #pragma unroll
        for (int r = 0; r < 4; ++r) {
            int row = w * 16 + g * 4 + r;
            xout[((size_t)(b * 64 + row)) * 256 + h * 32 + n * 16 + l15] =
                o[n][r] / rsum[r];
        }
    }
}

// ---------------------------------------------------------------------------
// Weight prep: src fp32 [K][N] row-major -> dst bf16 [N][K] (transposed).
// 64x64 tiles, grid (K/64, N/64).
// ---------------------------------------------------------------------------
__global__ __launch_bounds__(256) void prep_wT(const float* __restrict__ src,
                                               unsigned short* __restrict__ dst,
                                               int K, int N)
{
    __shared__ float tile[64][68];
    const int bk = blockIdx.x * 64, bn = blockIdx.y * 64;
    const int t = threadIdx.x;
    const int r0 = t >> 4;
    const int c4 = (t & 15) * 4;
    #pragma unroll
    for (int p = 0; p < 4; ++p) {
        int row = r0 + p * 16;
        float4 d = *(const float4*)(src + (size_t)(bk + row) * N + bn + c4);
        tile[row][c4 + 0] = d.x; tile[row][c4 + 1] = d.y;
        tile[row][c4 + 2] = d.z; tile[row][c4 + 3] = d.w;
    }
    __syncthreads();
    #pragma unroll
    for (int p = 0; p < 4; ++p) {
        int n = r0 + p * 16;
        unsigned short* o = dst + (size_t)(bn + n) * K + bk + c4;
        o[0] = f2bf(tile[c4 + 0][n]);
        o[1] = f2bf(tile[c4 + 1][n]);
        o[2] = f2bf(tile[c4 + 2][n]);
        o[3] = f2bf(tile[c4 + 3][n]);
    }
}

// ---------------------------------------------------------------------------
// Fused MLP: xio (fp32 [65536][256], also residual & output, per-block-private
// 128-row panels). wt1 bf16 [1024][256], wt2 bf16 [256][1024].
// 512 threads = 8 waves. Hidden processed in 16 chunks of 64.
//   h-compute: waves 4M x 2N over 128x64; x frags live in registers.
//   out-accum: waves 2M x 4N over 128x256; w frags read direct from L2.
// ---------------------------------------------------------------------------
__global__ __launch_bounds__(512, 2) void mlp_fused(
    float* xio,
    const unsigned short* __restrict__ wt1, const float* __restrict__ b1,
    const unsigned short* __restrict__ wt2, const float* __restrict__ b2)
{
    __shared__ unsigned short Hs[2][128][72];

    const int tid  = threadIdx.x;
    const int lane = tid & 63;
    const int l15  = lane & 15;
    const int g    = lane >> 4;
    const int wid  = tid >> 6;
    const int wmh  = wid >> 1, wnh = wid & 1;   // h-compute wave grid 4x2
    const int wmo  = wid >> 2, wno = wid & 3;   // out-accum wave grid 2x4

    const size_t rowbase = (size_t)blockIdx.x * 128;

    // ---- x fragments -> registers (one-time, 64 VGPRs) ----
    bf16x8 xf[2][8];
    #pragma unroll
    for (int mt = 0; mt < 2; ++mt) {
        const float* xr = xio + (rowbase + wmh * 32 + mt * 16 + l15) * 256;
        #pragma unroll
        for (int ks = 0; ks < 8; ++ks) {
            float4 a0 = *(const float4*)(xr + ks * 32 + g * 8);
            float4 a1 = *(const float4*)(xr + ks * 32 + g * 8 + 4);
            xf[mt][ks] = pack8(a0, a1);
        }
    }

    f32x4 oacc[4][4] = {};

    for (int hc = 0; hc < 16; ++hc) {
        // ---- h chunk: 128x64 = x(128x256) @ w1c(256x64) ----
        f32x4 hacc[2][2] = {};
        const unsigned short* w1r0 = wt1 + (size_t)(hc * 64 + wnh * 32 + l15) * 256;
        #pragma unroll
        for (int ks = 0; ks < 8; ++ks) {
            bf16x8 bf0 = *(const bf16x8*)(w1r0 + ks * 32 + g * 8);
            bf16x8 bf1 = *(const bf16x8*)(w1r0 + 16 * 256 + ks * 32 + g * 8);
            hacc[0][0] = mfma_bf16(xf[0][ks], bf0, hacc[0][0]);
            hacc[0][1] = mfma_bf16(xf[0][ks], bf1, hacc[0][1]);
            hacc[1][0] = mfma_bf16(xf[1][ks], bf0, hacc[1][0]);
            hacc[1][1] = mfma_bf16(xf[1][ks], bf1, hacc[1][1]);
        }

        // ---- bias + exact GELU -> bf16 -> LDS (double-buffered) ----
        #pragma unroll
        for (int nt = 0; nt < 2; ++nt) {
            int coll = wnh * 32 + nt * 16 + l15;
            float bias = b1[hc * 64 + coll];
            #pragma unroll
            for (int mt = 0; mt < 2; ++mt) {
                #pragma unroll
                for (int r = 0; r < 4; ++r) {
                    float vv = hacc[mt][nt][r] + bias;
                    vv = 0.5f * vv * (1.0f + erff(vv * 0.70710678118654752f));
                    Hs[hc & 1][wmh * 32 + mt * 16 + g * 4 + r][coll] = f2bf(vv);
                }
            }
        }
        __syncthreads();

        // ---- out += h(128x64) @ w2c(64x256) ----
        #pragma unroll
        for (int ks2 = 0; ks2 < 2; ++ks2) {
            bf16x8 aF[4], bF[4];
            #pragma unroll
            for (int t = 0; t < 4; ++t)
                aF[t] = *(const bf16x8*)&Hs[hc & 1][wmo * 64 + t * 16 + l15][ks2 * 32 + g * 8];
            #pragma unroll
            for (int t = 0; t < 4; ++t)
                bF[t] = *(const bf16x8*)(wt2 + (size_t)(wno * 64 + t * 16 + l15) * 1024
                                             + hc * 64 + ks2 * 32 + g * 8);
            #pragma unroll
            for (int mt = 0; mt < 4; ++mt)
                #pragma unroll
                for (int nt = 0; nt < 4; ++nt)
                    oacc[mt][nt] = mfma_bf16(aF[mt], bF[nt], oacc[mt][nt]);
        }
        // no second barrier: Hs is double-buffered; the single barrier per
        // chunk orders write(i)->read(i) and read(i)->write(i+2).
    }

    // ---- epilogue: out = oacc + b2 + residual ----
    #pragma unroll
    for (int nt = 0; nt < 4; ++nt) {
        int col = wno * 64 + nt * 16 + l15;
        float bias = b2[col];
        #pragma unroll
        for (int mt = 0; mt < 4; ++mt) {
            #pragma unroll
            for (int r = 0; r < 4; ++r) {
                size_t idx = (rowbase + wmo * 64 + mt * 16 + g * 4 + r) * 256 + col;
                xio[idx] = oacc[mt][nt][r] + bias + xio[idx];
            }
        }
    }
}

// ---------------------------------------------------------------------------
extern "C" void kernel_launch(void* const* d_in, const int* in_sizes, int n_in,
                              void* d_out, int out_size, void* d_ws, size_t ws_size,
                              hipStream_t stream)
{
    const float* q    = (const float*)d_in[0];
    const float* k    = (const float*)d_in[1];
    const float* v    = (const float*)d_in[2];
    const float* mask = (const float*)d_in[3];
    const float* w1   = (const float*)d_in[6];
    const float* b1   = (const float*)d_in[7];
    const float* w2   = (const float*)d_in[8];
    const float* b2   = (const float*)d_in[9];

    float* xio = (float*)d_out;

    unsigned short* wt1 = (unsigned short*)d_ws;                 // [1024][256] bf16
    unsigned short* wt2 = wt1 + (size_t)1024 * 256;              // [256][1024] bf16

    // weight transpose+convert (tiny, L2-resident)
    prep_wT<<<dim3(4, 16), 256, 0, stream>>>(w1, wt1, 256, 1024);
    prep_wT<<<dim3(16, 4), 256, 0, stream>>>(w2, wt2, 1024, 256);

    // attention -> xio (fp32)
    attn_kernel<<<8192, 256, 0, stream>>>(q, k, v, mask, xio);

    // fused MLP + residual, in place on xio
    mlp_fused<<<512, 512, 0, stream>>>(xio, wt1, b1, wt2, b2);
}

// Round 3
// 297.967 us; speedup vs baseline: 1.4327x; 1.0017x over previous
//
#include <hip/hip_runtime.h>
#include <hip/hip_bf16.h>
#include <cstdint>
#include <cstddef>

typedef __attribute__((ext_vector_type(8))) short bf16x8;   // 8 bf16 in 4 VGPRs
typedef __attribute__((ext_vector_type(4))) float f32x4;

static __device__ __forceinline__ unsigned short f2bf(float f) {
    union { float f; unsigned int u; } x; x.f = f;
    unsigned int u = x.u;
    unsigned int r = (u + 0x7FFFu + ((u >> 16) & 1u)) >> 16;  // RNE
    return (unsigned short)r;
}

static __device__ __forceinline__ f32x4 mfma_bf16(bf16x8 a, bf16x8 b, f32x4 c) {
    return __builtin_amdgcn_mfma_f32_16x16x32_bf16(a, b, c, 0, 0, 0);
}

static __device__ __forceinline__ bf16x8 pack8(float4 a, float4 b) {
    bf16x8 f;
    f[0]=(short)f2bf(a.x); f[1]=(short)f2bf(a.y); f[2]=(short)f2bf(a.z); f[3]=(short)f2bf(a.w);
    f[4]=(short)f2bf(b.x); f[5]=(short)f2bf(b.y); f[6]=(short)f2bf(b.z); f[7]=(short)f2bf(b.w);
    return f;
}

// Branchless exact-erf GELU: Abramowitz-Stegun 7.1.26 (|erf err| < 1.5e-7).
// ~15 VALU ops + v_rcp + v_exp, no divergence.
static __device__ __forceinline__ float gelu_erf(float v) {
    float s = v * 0.70710678118654752f;
    float a = fabsf(s);
    float t = __builtin_amdgcn_rcpf(1.0f + 0.3275911f * a);
    float poly = ((((1.061405429f * t - 1.453152027f) * t + 1.421413741f) * t
                   - 0.284496736f) * t + 0.254829592f) * t;
    float e = 1.0f - poly * __expf(-a * a);          // erf(a), a>=0
    float erfv = copysignf(e, s);
    return 0.5f * v * (1.0f + erfv);
}

// ---------------------------------------------------------------------------
// Attention: one block per (window b, head h). 4 waves, wave w owns rows
// 16w..16w+15 of the 64x64 score tile. Writes fp32 attention output to xout.
// ---------------------------------------------------------------------------
__global__ __launch_bounds__(256) void attn_kernel(
    const float* __restrict__ q, const float* __restrict__ k,
    const float* __restrict__ v, const float* __restrict__ mask,
    float* __restrict__ xout)
{
    __shared__ unsigned short Qs[64][40];
    __shared__ unsigned short Ks[64][40];
    __shared__ unsigned short Vt[32][72];
    __shared__ unsigned short Ps[64][72];

    const int tid  = threadIdx.x;
    const int b    = blockIdx.x >> 3;
    const int h    = blockIdx.x & 7;
    const int lane = tid & 63;
    const int l15  = lane & 15;
    const int g    = lane >> 4;
    const int w    = tid >> 6;

    {
        int row = tid >> 2;
        int seg = tid & 3;
        size_t base = ((size_t)(b * 64 + row)) * 256 + h * 32 + seg * 8;

        float4 a0 = *(const float4*)(q + base);
        float4 a1 = *(const float4*)(q + base + 4);
        unsigned short* p = &Qs[row][seg * 8];
        p[0]=f2bf(a0.x); p[1]=f2bf(a0.y); p[2]=f2bf(a0.z); p[3]=f2bf(a0.w);
        p[4]=f2bf(a1.x); p[5]=f2bf(a1.y); p[6]=f2bf(a1.z); p[7]=f2bf(a1.w);

        a0 = *(const float4*)(k + base);
        a1 = *(const float4*)(k + base + 4);
        p = &Ks[row][seg * 8];
        p[0]=f2bf(a0.x); p[1]=f2bf(a0.y); p[2]=f2bf(a0.z); p[3]=f2bf(a0.w);
        p[4]=f2bf(a1.x); p[5]=f2bf(a1.y); p[6]=f2bf(a1.z); p[7]=f2bf(a1.w);

        a0 = *(const float4*)(v + base);
        a1 = *(const float4*)(v + base + 4);
        int c = seg * 8;
        Vt[c + 0][row] = f2bf(a0.x);
        Vt[c + 1][row] = f2bf(a0.y);
        Vt[c + 2][row] = f2bf(a0.z);
        Vt[c + 3][row] = f2bf(a0.w);
        Vt[c + 4][row] = f2bf(a1.x);
        Vt[c + 5][row] = f2bf(a1.y);
        Vt[c + 6][row] = f2bf(a1.z);
        Vt[c + 7][row] = f2bf(a1.w);
    }
    __syncthreads();

    f32x4 s[4];
    {
        bf16x8 aQ = *(const bf16x8*)&Qs[w * 16 + l15][g * 8];
        #pragma unroll
        for (int ct = 0; ct < 4; ++ct) {
            bf16x8 bK = *(const bf16x8*)&Ks[ct * 16 + l15][g * 8];
            f32x4 z = {0.f, 0.f, 0.f, 0.f};
            s[ct] = mfma_bf16(aQ, bK, z);
        }
    }

    const float* mbase = mask + (size_t)(b & 63) * 4096;
    const float INV = 0.17677669529663688f;
    float rsum[4];
    #pragma unroll
    for (int r = 0; r < 4; ++r) {
        int row = w * 16 + g * 4 + r;
        float pr[4];
        #pragma unroll
        for (int ct = 0; ct < 4; ++ct)
            pr[ct] = (s[ct][r] + mbase[row * 64 + ct * 16 + l15]) * INV;
        float m = fmaxf(fmaxf(pr[0], pr[1]), fmaxf(pr[2], pr[3]));
        #pragma unroll
        for (int off = 1; off < 16; off <<= 1)
            m = fmaxf(m, __shfl_xor(m, off));
        float sum = 0.f;
        #pragma unroll
        for (int ct = 0; ct < 4; ++ct) { pr[ct] = __expf(pr[ct] - m); sum += pr[ct]; }
        #pragma unroll
        for (int off = 1; off < 16; off <<= 1)
            sum += __shfl_xor(sum, off);
        rsum[r] = sum;
        #pragma unroll
        for (int ct = 0; ct < 4; ++ct)
            Ps[row][ct * 16 + l15] = f2bf(pr[ct]);
    }

    f32x4 o[2] = {};
    #pragma unroll
    for (int ks = 0; ks < 2; ++ks) {
        bf16x8 pa = *(const bf16x8*)&Ps[w * 16 + l15][ks * 32 + g * 8];
        #pragma unroll
        for (int n = 0; n < 2; ++n) {
            bf16x8 vb = *(const bf16x8*)&Vt[n * 16 + l15][ks * 32 + g * 8];
            o[n] = mfma_bf16(pa, vb, o[n]);
        }
    }

    #pragma unroll
    for (int n = 0; n < 2; ++n) {
        #pragma unroll
        for (int r = 0; r < 4; ++r) {
            int row = w * 16 + g * 4 + r;
            xout[((size_t)(b * 64 + row)) * 256 + h * 32 + n * 16 + l15] =
                o[n][r] / rsum[r];
        }
    }
}

// ---------------------------------------------------------------------------
// Weight prep: src fp32 [K][N] row-major -> dst bf16 [N][K] (transposed).
// ---------------------------------------------------------------------------
__global__ __launch_bounds__(256) void prep_wT(const float* __restrict__ src,
                                               unsigned short* __restrict__ dst,
                                               int K, int N)
{
    __shared__ float tile[64][68];
    const int bk = blockIdx.x * 64, bn = blockIdx.y * 64;
    const int t = threadIdx.x;
    const int r0 = t >> 4;
    const int c4 = (t & 15) * 4;
    #pragma unroll
    for (int p = 0; p < 4; ++p) {
        int row = r0 + p * 16;
        float4 d = *(const float4*)(src + (size_t)(bk + row) * N + bn + c4);
        tile[row][c4 + 0] = d.x; tile[row][c4 + 1] = d.y;
        tile[row][c4 + 2] = d.z; tile[row][c4 + 3] = d.w;
    }
    __syncthreads();
    #pragma unroll
    for (int p = 0; p < 4; ++p) {
        int n = r0 + p * 16;
        unsigned short* o = dst + (size_t)(bn + n) * K + bk + c4;
        o[0] = f2bf(tile[c4 + 0][n]);
        o[1] = f2bf(tile[c4 + 1][n]);
        o[2] = f2bf(tile[c4 + 2][n]);
        o[3] = f2bf(tile[c4 + 3][n]);
    }
}

// ---------------------------------------------------------------------------
// Fused MLP. 512 threads = 8 waves, 128-row panel per block.
// Per hidden chunk of 64:
//   h-phase: waves 4M x 2N; x frags in registers, w1 frags batched from L2.
//   out-phase: waves 2M x 4N; w2 loads issued FIRST after barrier so their
//   latency hides under the h ds_reads + MFMA issue.
// ---------------------------------------------------------------------------
__global__ __launch_bounds__(512, 2) void mlp_fused(
    float* xio,
    const unsigned short* __restrict__ wt1, const float* __restrict__ b1,
    const unsigned short* __restrict__ wt2, const float* __restrict__ b2)
{
    __shared__ unsigned short Hs[2][128][72];

    const int tid  = threadIdx.x;
    const int lane = tid & 63;
    const int l15  = lane & 15;
    const int g    = lane >> 4;
    const int wid  = tid >> 6;
    const int wmh  = wid >> 1, wnh = wid & 1;   // h-phase wave grid 4x2
    const int wmo  = wid >> 2, wno = wid & 3;   // out-phase wave grid 2x4

    const size_t rowbase = (size_t)blockIdx.x * 128;

    // ---- x fragments -> registers (one-time) ----
    bf16x8 xf[2][8];
    #pragma unroll
    for (int mt = 0; mt < 2; ++mt) {
        const float* xr = xio + (rowbase + wmh * 32 + mt * 16 + l15) * 256;
        #pragma unroll
        for (int ks = 0; ks < 8; ++ks) {
            float4 a0 = *(const float4*)(xr + ks * 32 + g * 8);
            float4 a1 = *(const float4*)(xr + ks * 32 + g * 8 + 4);
            xf[mt][ks] = pack8(a0, a1);
        }
    }

    f32x4 oacc[4][4] = {};

    for (int hc = 0; hc < 16; ++hc) {
        // ---- h-phase: batch-issue all 16 w1 loads, then MFMA ----
        const unsigned short* w1r0 = wt1 + (size_t)(hc * 64 + wnh * 32 + l15) * 256;
        bf16x8 w1f[2][8];
        #pragma unroll
        for (int ks = 0; ks < 8; ++ks) {
            w1f[0][ks] = *(const bf16x8*)(w1r0 + ks * 32 + g * 8);
            w1f[1][ks] = *(const bf16x8*)(w1r0 + 16 * 256 + ks * 32 + g * 8);
        }
        f32x4 hacc[2][2] = {};
        #pragma unroll
        for (int ks = 0; ks < 8; ++ks) {
            hacc[0][0] = mfma_bf16(xf[0][ks], w1f[0][ks], hacc[0][0]);
            hacc[0][1] = mfma_bf16(xf[0][ks], w1f[1][ks], hacc[0][1]);
            hacc[1][0] = mfma_bf16(xf[1][ks], w1f[0][ks], hacc[1][0]);
            hacc[1][1] = mfma_bf16(xf[1][ks], w1f[1][ks], hacc[1][1]);
        }

        // ---- bias + branchless GELU -> bf16 -> LDS (double-buffered) ----
        #pragma unroll
        for (int nt = 0; nt < 2; ++nt) {
            int coll = wnh * 32 + nt * 16 + l15;
            float bias = b1[hc * 64 + coll];
            #pragma unroll
            for (int mt = 0; mt < 2; ++mt) {
                #pragma unroll
                for (int r = 0; r < 4; ++r) {
                    float vv = gelu_erf(hacc[mt][nt][r] + bias);
                    Hs[hc & 1][wmh * 32 + mt * 16 + g * 4 + r][coll] = f2bf(vv);
                }
            }
        }
        __syncthreads();

        // ---- out-phase: w2 loads FIRST (hide L2 latency), then h ds_reads ----
        bf16x8 bF[2][4];
        #pragma unroll
        for (int ks2 = 0; ks2 < 2; ++ks2)
            #pragma unroll
            for (int t = 0; t < 4; ++t)
                bF[ks2][t] = *(const bf16x8*)(wt2 + (size_t)(wno * 64 + t * 16 + l15) * 1024
                                                  + hc * 64 + ks2 * 32 + g * 8);
        bf16x8 aF[2][4];
        #pragma unroll
        for (int ks2 = 0; ks2 < 2; ++ks2)
            #pragma unroll
            for (int t = 0; t < 4; ++t)
                aF[ks2][t] = *(const bf16x8*)&Hs[hc & 1][wmo * 64 + t * 16 + l15][ks2 * 32 + g * 8];
        #pragma unroll
        for (int ks2 = 0; ks2 < 2; ++ks2)
            #pragma unroll
            for (int mt = 0; mt < 4; ++mt)
                #pragma unroll
                for (int nt = 0; nt < 4; ++nt)
                    oacc[mt][nt] = mfma_bf16(aF[ks2][mt], bF[ks2][nt], oacc[mt][nt]);
        // Hs double-buffered: single barrier per chunk suffices.
    }

    // ---- epilogue: out = oacc + b2 + residual ----
    #pragma unroll
    for (int nt = 0; nt < 4; ++nt) {
        int col = wno * 64 + nt * 16 + l15;
        float bias = b2[col];
        #pragma unroll
        for (int mt = 0; mt < 4; ++mt) {
            #pragma unroll
            for (int r = 0; r < 4; ++r) {
                size_t idx = (rowbase + wmo * 64 + mt * 16 + g * 4 + r) * 256 + col;
                xio[idx] = oacc[mt][nt][r] + bias + xio[idx];
            }
        }
    }
}

// ---------------------------------------------------------------------------
extern "C" void kernel_launch(void* const* d_in, const int* in_sizes, int n_in,
                              void* d_out, int out_size, void* d_ws, size_t ws_size,
                              hipStream_t stream)
{
    const float* q    = (const float*)d_in[0];
    const float* k    = (const float*)d_in[1];
    const float* v    = (const float*)d_in[2];
    const float* mask = (const float*)d_in[3];
    const float* w1   = (const float*)d_in[6];
    const float* b1   = (const float*)d_in[7];
    const float* w2   = (const float*)d_in[8];
    const float* b2   = (const float*)d_in[9];

    float* xio = (float*)d_out;

    unsigned short* wt1 = (unsigned short*)d_ws;                 // [1024][256] bf16
    unsigned short* wt2 = wt1 + (size_t)1024 * 256;              // [256][1024] bf16

    prep_wT<<<dim3(4, 16), 256, 0, stream>>>(w1, wt1, 256, 1024);
    prep_wT<<<dim3(16, 4), 256, 0, stream>>>(w2, wt2, 1024, 256);

    attn_kernel<<<8192, 256, 0, stream>>>(q, k, v, mask, xio);

    mlp_fused<<<512, 512, 0, stream>>>(xio, wt1, b1, wt2, b2);
}

// Round 4
// 188.659 us; speedup vs baseline: 2.2629x; 1.5794x over previous
//
#include <hip/hip_runtime.h>
#include <hip/hip_bf16.h>
#include <cstdint>
#include <cstddef>

typedef __attribute__((ext_vector_type(8))) short bf16x8;   // 8 bf16 in 4 VGPRs
typedef __attribute__((ext_vector_type(4))) float f32x4;

static __device__ __forceinline__ unsigned short f2bf(float f) {
    union { float f; unsigned int u; } x; x.f = f;
    unsigned int u = x.u;
    unsigned int r = (u + 0x7FFFu + ((u >> 16) & 1u)) >> 16;  // RNE
    return (unsigned short)r;
}

static __device__ __forceinline__ f32x4 mfma_bf16(bf16x8 a, bf16x8 b, f32x4 c) {
    return __builtin_amdgcn_mfma_f32_16x16x32_bf16(a, b, c, 0, 0, 0);
}

static __device__ __forceinline__ bf16x8 pack8(float4 a, float4 b) {
    bf16x8 f;
    f[0]=(short)f2bf(a.x); f[1]=(short)f2bf(a.y); f[2]=(short)f2bf(a.z); f[3]=(short)f2bf(a.w);
    f[4]=(short)f2bf(b.x); f[5]=(short)f2bf(b.y); f[6]=(short)f2bf(b.z); f[7]=(short)f2bf(b.w);
    return f;
}

// Branchless exact-erf GELU (A&S 7.1.26, |erf err| < 1.5e-7).
static __device__ __forceinline__ float gelu_erf(float v) {
    float s = v * 0.70710678118654752f;
    float a = fabsf(s);
    float t = __builtin_amdgcn_rcpf(1.0f + 0.3275911f * a);
    float poly = ((((1.061405429f * t - 1.453152027f) * t + 1.421413741f) * t
                   - 0.284496736f) * t + 0.254829592f) * t;
    float e = 1.0f - poly * __expf(-a * a);
    float erfv = copysignf(e, s);
    return 0.5f * v * (1.0f + erfv);
}

// async 16B global -> LDS (linear dest: wave-uniform base + lane*16)
static __device__ __forceinline__ void load_lds16(const unsigned short* g, unsigned short* l) {
    __builtin_amdgcn_global_load_lds(
        (const __attribute__((address_space(1))) unsigned int*)g,
        (__attribute__((address_space(3))) unsigned int*)l, 16, 0, 0);
}

// ---------------------------------------------------------------------------
// Attention (unchanged — at its HBM floor): one block per (window, head).
// ---------------------------------------------------------------------------
__global__ __launch_bounds__(256) void attn_kernel(
    const float* __restrict__ q, const float* __restrict__ k,
    const float* __restrict__ v, const float* __restrict__ mask,
    float* __restrict__ xout)
{
    __shared__ unsigned short Qs[64][40];
    __shared__ unsigned short Ks[64][40];
    __shared__ unsigned short Vt[32][72];
    __shared__ unsigned short Ps[64][72];

    const int tid  = threadIdx.x;
    const int b    = blockIdx.x >> 3;
    const int h    = blockIdx.x & 7;
    const int lane = tid & 63;
    const int l15  = lane & 15;
    const int g    = lane >> 4;
    const int w    = tid >> 6;

    {
        int row = tid >> 2;
        int seg = tid & 3;
        size_t base = ((size_t)(b * 64 + row)) * 256 + h * 32 + seg * 8;

        float4 a0 = *(const float4*)(q + base);
        float4 a1 = *(const float4*)(q + base + 4);
        unsigned short* p = &Qs[row][seg * 8];
        p[0]=f2bf(a0.x); p[1]=f2bf(a0.y); p[2]=f2bf(a0.z); p[3]=f2bf(a0.w);
        p[4]=f2bf(a1.x); p[5]=f2bf(a1.y); p[6]=f2bf(a1.z); p[7]=f2bf(a1.w);

        a0 = *(const float4*)(k + base);
        a1 = *(const float4*)(k + base + 4);
        p = &Ks[row][seg * 8];
        p[0]=f2bf(a0.x); p[1]=f2bf(a0.y); p[2]=f2bf(a0.z); p[3]=f2bf(a0.w);
        p[4]=f2bf(a1.x); p[5]=f2bf(a1.y); p[6]=f2bf(a1.z); p[7]=f2bf(a1.w);

        a0 = *(const float4*)(v + base);
        a1 = *(const float4*)(v + base + 4);
        int c = seg * 8;
        Vt[c + 0][row] = f2bf(a0.x);
        Vt[c + 1][row] = f2bf(a0.y);
        Vt[c + 2][row] = f2bf(a0.z);
        Vt[c + 3][row] = f2bf(a0.w);
        Vt[c + 4][row] = f2bf(a1.x);
        Vt[c + 5][row] = f2bf(a1.y);
        Vt[c + 6][row] = f2bf(a1.z);
        Vt[c + 7][row] = f2bf(a1.w);
    }
    __syncthreads();

    f32x4 s[4];
    {
        bf16x8 aQ = *(const bf16x8*)&Qs[w * 16 + l15][g * 8];
        #pragma unroll
        for (int ct = 0; ct < 4; ++ct) {
            bf16x8 bK = *(const bf16x8*)&Ks[ct * 16 + l15][g * 8];
            f32x4 z = {0.f, 0.f, 0.f, 0.f};
            s[ct] = mfma_bf16(aQ, bK, z);
        }
    }

    const float* mbase = mask + (size_t)(b & 63) * 4096;
    const float INV = 0.17677669529663688f;
    float rsum[4];
    #pragma unroll
    for (int r = 0; r < 4; ++r) {
        int row = w * 16 + g * 4 + r;
        float pr[4];
        #pragma unroll
        for (int ct = 0; ct < 4; ++ct)
            pr[ct] = (s[ct][r] + mbase[row * 64 + ct * 16 + l15]) * INV;
        float m = fmaxf(fmaxf(pr[0], pr[1]), fmaxf(pr[2], pr[3]));
        #pragma unroll
        for (int off = 1; off < 16; off <<= 1)
            m = fmaxf(m, __shfl_xor(m, off));
        float sum = 0.f;
        #pragma unroll
        for (int ct = 0; ct < 4; ++ct) { pr[ct] = __expf(pr[ct] - m); sum += pr[ct]; }
        #pragma unroll
        for (int off = 1; off < 16; off <<= 1)
            sum += __shfl_xor(sum, off);
        rsum[r] = sum;
        #pragma unroll
        for (int ct = 0; ct < 4; ++ct)
            Ps[row][ct * 16 + l15] = f2bf(pr[ct]);
    }

    f32x4 o[2] = {};
    #pragma unroll
    for (int ks = 0; ks < 2; ++ks) {
        bf16x8 pa = *(const bf16x8*)&Ps[w * 16 + l15][ks * 32 + g * 8];
        #pragma unroll
        for (int n = 0; n < 2; ++n) {
            bf16x8 vb = *(const bf16x8*)&Vt[n * 16 + l15][ks * 32 + g * 8];
            o[n] = mfma_bf16(pa, vb, o[n]);
        }
    }

    #pragma unroll
    for (int n = 0; n < 2; ++n) {
        #pragma unroll
        for (int r = 0; r < 4; ++r) {
            int row = w * 16 + g * 4 + r;
            xout[((size_t)(b * 64 + row)) * 256 + h * 32 + n * 16 + l15] =
                o[n][r] / rsum[r];
        }
    }
}

// ---------------------------------------------------------------------------
// Weight prep to FRAGMENT-ORDERED bf16 layout (one 32 KB panel per hidden
// chunk of 64). w1 src fp32 [256][1024]. Panel hc element order:
//   idx = ((((wnh*8+ks)*2+h)*16+l15)*4+g)*8 + e
//   maps (n = hc*64 + wnh*32 + h*16 + l15, k = ks*32 + g*8 + e).
// grid (kt=4, hc=16), 256 thr.
// ---------------------------------------------------------------------------
__global__ __launch_bounds__(256) void prep_w1(const float* __restrict__ src,
                                               unsigned short* __restrict__ dst)
{
    __shared__ float tile[64][65];              // [k_local][n_local]
    const int kt = blockIdx.x, hc = blockIdx.y;
    const int t = threadIdx.x;
    const int r0 = t >> 4, c4 = (t & 15) * 4;
    #pragma unroll
    for (int p = 0; p < 4; ++p) {
        int kk = r0 + p * 16;
        float4 d = *(const float4*)(src + (size_t)(kt * 64 + kk) * 1024 + hc * 64 + c4);
        tile[kk][c4+0]=d.x; tile[kk][c4+1]=d.y; tile[kk][c4+2]=d.z; tile[kk][c4+3]=d.w;
    }
    __syncthreads();
    #pragma unroll
    for (int i = 0; i < 2; ++i) {
        int f = t + 256 * i;                    // 0..511
        int wnh = f >> 8;
        int r   = f & 255;
        int ksl = r >> 7;
        int h2  = (r >> 6) & 1;
        int r3  = r & 63;
        int l15v = r3 >> 2, gv = r3 & 3;
        int n_local = wnh * 32 + h2 * 16 + l15v;
        int k_local = ksl * 32 + gv * 8;
        int ks = kt * 2 + ksl;
        unsigned short tmp[8];
        #pragma unroll
        for (int e = 0; e < 8; ++e) tmp[e] = f2bf(tile[k_local + e][n_local]);
        size_t off = (size_t)hc * 16384 + ((size_t)((wnh * 8 + ks) * 2 + h2)) * 512
                   + (l15v * 4 + gv) * 8;
        *(bf16x8*)(dst + off) = *(const bf16x8*)tmp;
    }
}

// w2 src fp32 [1024][256]. Panel hc (64 k-rows) element order:
//   idx = ((((wno*2+ks2)*4+t)*16+l15)*4+g)*8 + e
//   maps (c = wno*64 + t*16 + l15, k_local = ks2*32 + g*8 + e).
// grid (wno=4, hc=16), 256 thr.
__global__ __launch_bounds__(256) void prep_w2(const float* __restrict__ src,
                                               unsigned short* __restrict__ dst)
{
    __shared__ float tile[64][65];              // [k_local][c_local]
    const int wno = blockIdx.x, hc = blockIdx.y;
    const int t = threadIdx.x;
    const int r0 = t >> 4, c4 = (t & 15) * 4;
    #pragma unroll
    for (int p = 0; p < 4; ++p) {
        int kk = r0 + p * 16;
        float4 d = *(const float4*)(src + (size_t)(hc * 64 + kk) * 256 + wno * 64 + c4);
        tile[kk][c4+0]=d.x; tile[kk][c4+1]=d.y; tile[kk][c4+2]=d.z; tile[kk][c4+3]=d.w;
    }
    __syncthreads();
    #pragma unroll
    for (int i = 0; i < 2; ++i) {
        int f = t + 256 * i;
        int ks2 = f >> 8;
        int r   = f & 255;
        int tq  = r >> 6;
        int r3  = r & 63;
        int l15v = r3 >> 2, gv = r3 & 3;
        int c_local = tq * 16 + l15v;
        int k_local = ks2 * 32 + gv * 8;
        unsigned short tmp[8];
        #pragma unroll
        for (int e = 0; e < 8; ++e) tmp[e] = f2bf(tile[k_local + e][c_local]);
        size_t off = (size_t)hc * 16384 + ((size_t)((wno * 2 + ks2) * 4 + tq)) * 512
                   + (l15v * 4 + gv) * 8;
        *(bf16x8*)(dst + off) = *(const bf16x8*)tmp;
    }
}

// ---------------------------------------------------------------------------
// Fused MLP v3. 512 thr = 8 waves, 128-row panel, 512 blocks (1/CU, 2 rounds).
// Weights DMA'd per chunk into LDS (frag-ordered, conflict-free ds_read_b128),
// double-buffered, prefetched one chunk ahead under compute.
// ---------------------------------------------------------------------------
__global__ __launch_bounds__(512, 2) void mlp_fused(
    const float* __restrict__ xin, float* __restrict__ xio,
    const unsigned short* __restrict__ wt1, const float* __restrict__ b1,
    const unsigned short* __restrict__ wt2, const float* __restrict__ b2)
{
    __shared__ unsigned short w1c[2][16384];    // 32 KB per buf, frag-ordered
    __shared__ unsigned short w2c[2][16384];
    __shared__ unsigned short Hs[128][72];

    const int tid  = threadIdx.x;
    const int lane = tid & 63;
    const int l15  = lane & 15;
    const int g    = lane >> 4;
    const int wid  = tid >> 6;
    const int wmh  = wid >> 1, wnh = wid & 1;   // h-phase wave grid 4x2
    const int wmo  = wid >> 2, wno = wid & 3;   // out-phase wave grid 2x4
    const int fb   = (l15 * 4 + g) * 8;         // frag offset within 1KB span

    const size_t rowbase = (size_t)blockIdx.x * 128;

    // stage one 32 KB frag-ordered panel: 4 x 16B per thread, linear
    auto stage = [&](const unsigned short* gbase, unsigned short* lbase) {
        #pragma unroll
        for (int i = 0; i < 4; ++i) {
            load_lds16(gbase + (i * 512 + tid) * 8,
                       lbase + (i * 512 + wid * 64) * 8);
        }
    };

    // prefetch chunk 0 weights
    stage(wt1, &w1c[0][0]);
    stage(wt2, &w2c[0][0]);

    // x fragments -> registers (one-time)
    bf16x8 xf[2][8];
    #pragma unroll
    for (int mt = 0; mt < 2; ++mt) {
        const float* xr = xin + (rowbase + wmh * 32 + mt * 16 + l15) * 256;
        #pragma unroll
        for (int ks = 0; ks < 8; ++ks) {
            float4 a0 = *(const float4*)(xr + ks * 32 + g * 8);
            float4 a1 = *(const float4*)(xr + ks * 32 + g * 8 + 4);
            xf[mt][ks] = pack8(a0, a1);
        }
    }

    f32x4 oacc[4][4] = {};

    for (int hc = 0; hc < 16; ++hc) {
        const int cur = hc & 1;
        __syncthreads();   // drains chunk-hc DMA (vmcnt0) + orders Hs reuse

        if (hc < 15) {     // prefetch next chunk into other buffer
            stage(wt1 + (size_t)(hc + 1) * 16384, &w1c[cur ^ 1][0]);
            stage(wt2 + (size_t)(hc + 1) * 16384, &w2c[cur ^ 1][0]);
        }

        // ---- h-phase: 128x64 = x @ w1c ----
        f32x4 hacc[2][2] = {};
        #pragma unroll
        for (int ks = 0; ks < 8; ++ks) {
            bf16x8 b0 = *(const bf16x8*)&w1c[cur][((wnh * 8 + ks) * 2 + 0) * 512 + fb];
            bf16x8 b1f = *(const bf16x8*)&w1c[cur][((wnh * 8 + ks) * 2 + 1) * 512 + fb];
            hacc[0][0] = mfma_bf16(xf[0][ks], b0,  hacc[0][0]);
            hacc[0][1] = mfma_bf16(xf[0][ks], b1f, hacc[0][1]);
            hacc[1][0] = mfma_bf16(xf[1][ks], b0,  hacc[1][0]);
            hacc[1][1] = mfma_bf16(xf[1][ks], b1f, hacc[1][1]);
        }

        // ---- bias + GELU -> bf16 -> Hs ----
        #pragma unroll
        for (int nt = 0; nt < 2; ++nt) {
            int coll = wnh * 32 + nt * 16 + l15;
            float bias = b1[hc * 64 + coll];
            #pragma unroll
            for (int mt = 0; mt < 2; ++mt) {
                #pragma unroll
                for (int r = 0; r < 4; ++r) {
                    float vv = gelu_erf(hacc[mt][nt][r] + bias);
                    Hs[wmh * 32 + mt * 16 + g * 4 + r][coll] = f2bf(vv);
                }
            }
        }
        __syncthreads();

        // ---- out-phase: oacc += h(128x64) @ w2c(64x256) ----
        #pragma unroll
        for (int ks2 = 0; ks2 < 2; ++ks2) {
            bf16x8 aF[4], bF[4];
            #pragma unroll
            for (int t = 0; t < 4; ++t)
                aF[t] = *(const bf16x8*)&Hs[wmo * 64 + t * 16 + l15][ks2 * 32 + g * 8];
            #pragma unroll
            for (int t = 0; t < 4; ++t)
                bF[t] = *(const bf16x8*)&w2c[cur][((wno * 2 + ks2) * 4 + t) * 512 + fb];
            #pragma unroll
            for (int mt = 0; mt < 4; ++mt)
                #pragma unroll
                for (int nt = 0; nt < 4; ++nt)
                    oacc[mt][nt] = mfma_bf16(aF[mt], bF[nt], oacc[mt][nt]);
        }
    }

    // ---- epilogue: out = oacc + b2 + residual ----
    #pragma unroll
    for (int nt = 0; nt < 4; ++nt) {
        int col = wno * 64 + nt * 16 + l15;
        float bias = b2[col];
        #pragma unroll
        for (int mt = 0; mt < 4; ++mt) {
            #pragma unroll
            for (int r = 0; r < 4; ++r) {
                size_t idx = (rowbase + wmo * 64 + mt * 16 + g * 4 + r) * 256 + col;
                xio[idx] = oacc[mt][nt][r] + bias + xio[idx];
            }
        }
    }
}

// ---------------------------------------------------------------------------
extern "C" void kernel_launch(void* const* d_in, const int* in_sizes, int n_in,
                              void* d_out, int out_size, void* d_ws, size_t ws_size,
                              hipStream_t stream)
{
    const float* q    = (const float*)d_in[0];
    const float* k    = (const float*)d_in[1];
    const float* v    = (const float*)d_in[2];
    const float* mask = (const float*)d_in[3];
    const float* w1   = (const float*)d_in[6];
    const float* b1   = (const float*)d_in[7];
    const float* w2   = (const float*)d_in[8];
    const float* b2   = (const float*)d_in[9];

    float* xio = (float*)d_out;

    unsigned short* wt1 = (unsigned short*)d_ws;                 // 16 chunks x 32 KB
    unsigned short* wt2 = wt1 + (size_t)1024 * 256;

    prep_w1<<<dim3(4, 16), 256, 0, stream>>>(w1, wt1);
    prep_w2<<<dim3(4, 16), 256, 0, stream>>>(w2, wt2);

    attn_kernel<<<8192, 256, 0, stream>>>(q, k, v, mask, xio);

    mlp_fused<<<512, 512, 0, stream>>>(xio, xio, wt1, b1, wt2, b2);
}

// Round 5
// 184.481 us; speedup vs baseline: 2.3141x; 1.0226x over previous
//
#include <hip/hip_runtime.h>
#include <hip/hip_bf16.h>
#include <cstdint>
#include <cstddef>

typedef __attribute__((ext_vector_type(8))) short bf16x8;   // 8 bf16 in 4 VGPRs
typedef __attribute__((ext_vector_type(4))) float f32x4;

static __device__ __forceinline__ unsigned short f2bf(float f) {
    union { float f; unsigned int u; } x; x.f = f;
    unsigned int u = x.u;
    unsigned int r = (u + 0x7FFFu + ((u >> 16) & 1u)) >> 16;  // RNE
    return (unsigned short)r;
}

static __device__ __forceinline__ f32x4 mfma_bf16(bf16x8 a, bf16x8 b, f32x4 c) {
    return __builtin_amdgcn_mfma_f32_16x16x32_bf16(a, b, c, 0, 0, 0);
}

static __device__ __forceinline__ bf16x8 pack8(float4 a, float4 b) {
    bf16x8 f;
    f[0]=(short)f2bf(a.x); f[1]=(short)f2bf(a.y); f[2]=(short)f2bf(a.z); f[3]=(short)f2bf(a.w);
    f[4]=(short)f2bf(b.x); f[5]=(short)f2bf(b.y); f[6]=(short)f2bf(b.z); f[7]=(short)f2bf(b.w);
    return f;
}

// Branchless exact-erf GELU (A&S 7.1.26, |erf err| < 1.5e-7).
static __device__ __forceinline__ float gelu_erf(float v) {
    float s = v * 0.70710678118654752f;
    float a = fabsf(s);
    float t = __builtin_amdgcn_rcpf(1.0f + 0.3275911f * a);
    float poly = ((((1.061405429f * t - 1.453152027f) * t + 1.421413741f) * t
                   - 0.284496736f) * t + 0.254829592f) * t;
    float e = 1.0f - poly * __expf(-a * a);
    float erfv = copysignf(e, s);
    return 0.5f * v * (1.0f + erfv);
}

// async 16B global -> LDS (linear dest: wave-uniform base + lane*16)
static __device__ __forceinline__ void load_lds16(const unsigned short* g, unsigned short* l) {
    __builtin_amdgcn_global_load_lds(
        (const __attribute__((address_space(1))) unsigned int*)g,
        (__attribute__((address_space(3))) unsigned int*)l, 16, 0, 0);
}

// ---------------------------------------------------------------------------
// Attention (unchanged — at its HBM floor): one block per (window, head).
// ---------------------------------------------------------------------------
__global__ __launch_bounds__(256) void attn_kernel(
    const float* __restrict__ q, const float* __restrict__ k,
    const float* __restrict__ v, const float* __restrict__ mask,
    float* __restrict__ xout)
{
    __shared__ unsigned short Qs[64][40];
    __shared__ unsigned short Ks[64][40];
    __shared__ unsigned short Vt[32][72];
    __shared__ unsigned short Ps[64][72];

    const int tid  = threadIdx.x;
    const int b    = blockIdx.x >> 3;
    const int h    = blockIdx.x & 7;
    const int lane = tid & 63;
    const int l15  = lane & 15;
    const int g    = lane >> 4;
    const int w    = tid >> 6;

    {
        int row = tid >> 2;
        int seg = tid & 3;
        size_t base = ((size_t)(b * 64 + row)) * 256 + h * 32 + seg * 8;

        float4 a0 = *(const float4*)(q + base);
        float4 a1 = *(const float4*)(q + base + 4);
        unsigned short* p = &Qs[row][seg * 8];
        p[0]=f2bf(a0.x); p[1]=f2bf(a0.y); p[2]=f2bf(a0.z); p[3]=f2bf(a0.w);
        p[4]=f2bf(a1.x); p[5]=f2bf(a1.y); p[6]=f2bf(a1.z); p[7]=f2bf(a1.w);

        a0 = *(const float4*)(k + base);
        a1 = *(const float4*)(k + base + 4);
        p = &Ks[row][seg * 8];
        p[0]=f2bf(a0.x); p[1]=f2bf(a0.y); p[2]=f2bf(a0.z); p[3]=f2bf(a0.w);
        p[4]=f2bf(a1.x); p[5]=f2bf(a1.y); p[6]=f2bf(a1.z); p[7]=f2bf(a1.w);

        a0 = *(const float4*)(v + base);
        a1 = *(const float4*)(v + base + 4);
        int c = seg * 8;
        Vt[c + 0][row] = f2bf(a0.x);
        Vt[c + 1][row] = f2bf(a0.y);
        Vt[c + 2][row] = f2bf(a0.z);
        Vt[c + 3][row] = f2bf(a0.w);
        Vt[c + 4][row] = f2bf(a1.x);
        Vt[c + 5][row] = f2bf(a1.y);
        Vt[c + 6][row] = f2bf(a1.z);
        Vt[c + 7][row] = f2bf(a1.w);
    }
    __syncthreads();

    f32x4 s[4];
    {
        bf16x8 aQ = *(const bf16x8*)&Qs[w * 16 + l15][g * 8];
        #pragma unroll
        for (int ct = 0; ct < 4; ++ct) {
            bf16x8 bK = *(const bf16x8*)&Ks[ct * 16 + l15][g * 8];
            f32x4 z = {0.f, 0.f, 0.f, 0.f};
            s[ct] = mfma_bf16(aQ, bK, z);
        }
    }

    const float* mbase = mask + (size_t)(b & 63) * 4096;
    const float INV = 0.17677669529663688f;
    float rsum[4];
    #pragma unroll
    for (int r = 0; r < 4; ++r) {
        int row = w * 16 + g * 4 + r;
        float pr[4];
        #pragma unroll
        for (int ct = 0; ct < 4; ++ct)
            pr[ct] = (s[ct][r] + mbase[row * 64 + ct * 16 + l15]) * INV;
        float m = fmaxf(fmaxf(pr[0], pr[1]), fmaxf(pr[2], pr[3]));
        #pragma unroll
        for (int off = 1; off < 16; off <<= 1)
            m = fmaxf(m, __shfl_xor(m, off));
        float sum = 0.f;
        #pragma unroll
        for (int ct = 0; ct < 4; ++ct) { pr[ct] = __expf(pr[ct] - m); sum += pr[ct]; }
        #pragma unroll
        for (int off = 1; off < 16; off <<= 1)
            sum += __shfl_xor(sum, off);
        rsum[r] = sum;
        #pragma unroll
        for (int ct = 0; ct < 4; ++ct)
            Ps[row][ct * 16 + l15] = f2bf(pr[ct]);
    }

    f32x4 o[2] = {};
    #pragma unroll
    for (int ks = 0; ks < 2; ++ks) {
        bf16x8 pa = *(const bf16x8*)&Ps[w * 16 + l15][ks * 32 + g * 8];
        #pragma unroll
        for (int n = 0; n < 2; ++n) {
            bf16x8 vb = *(const bf16x8*)&Vt[n * 16 + l15][ks * 32 + g * 8];
            o[n] = mfma_bf16(pa, vb, o[n]);
        }
    }

    #pragma unroll
    for (int n = 0; n < 2; ++n) {
        #pragma unroll
        for (int r = 0; r < 4; ++r) {
            int row = w * 16 + g * 4 + r;
            xout[((size_t)(b * 64 + row)) * 256 + h * 32 + n * 16 + l15] =
                o[n][r] / rsum[r];
        }
    }
}

// ---------------------------------------------------------------------------
// Weight prep, FRAGMENT-ORDERED. Frag order within each 1KB tile-span is now
// (g*16 + l15) so a quarter-wave's b128 reads are 256B-contiguous (conflict-
// free), instead of (l15*4+g) which strided 64B (8-way bank conflict).
// ---------------------------------------------------------------------------
__global__ __launch_bounds__(256) void prep_w1(const float* __restrict__ src,
                                               unsigned short* __restrict__ dst)
{
    __shared__ float tile[64][65];              // [k_local][n_local]
    const int kt = blockIdx.x, hc = blockIdx.y;
    const int t = threadIdx.x;
    const int r0 = t >> 4, c4 = (t & 15) * 4;
    #pragma unroll
    for (int p = 0; p < 4; ++p) {
        int kk = r0 + p * 16;
        float4 d = *(const float4*)(src + (size_t)(kt * 64 + kk) * 1024 + hc * 64 + c4);
        tile[kk][c4+0]=d.x; tile[kk][c4+1]=d.y; tile[kk][c4+2]=d.z; tile[kk][c4+3]=d.w;
    }
    __syncthreads();
    #pragma unroll
    for (int i = 0; i < 2; ++i) {
        int f = t + 256 * i;                    // 0..511
        int wnh = f >> 8;
        int r   = f & 255;
        int ksl = r >> 7;
        int h2  = (r >> 6) & 1;
        int r3  = r & 63;
        int l15v = r3 >> 2, gv = r3 & 3;
        int n_local = wnh * 32 + h2 * 16 + l15v;
        int k_local = ksl * 32 + gv * 8;
        int ks = kt * 2 + ksl;
        unsigned short tmp[8];
        #pragma unroll
        for (int e = 0; e < 8; ++e) tmp[e] = f2bf(tile[k_local + e][n_local]);
        size_t off = (size_t)hc * 16384 + ((size_t)((wnh * 8 + ks) * 2 + h2)) * 512
                   + (gv * 16 + l15v) * 8;
        *(bf16x8*)(dst + off) = *(const bf16x8*)tmp;
    }
}

__global__ __launch_bounds__(256) void prep_w2(const float* __restrict__ src,
                                               unsigned short* __restrict__ dst)
{
    __shared__ float tile[64][65];              // [k_local][c_local]
    const int wno = blockIdx.x, hc = blockIdx.y;
    const int t = threadIdx.x;
    const int r0 = t >> 4, c4 = (t & 15) * 4;
    #pragma unroll
    for (int p = 0; p < 4; ++p) {
        int kk = r0 + p * 16;
        float4 d = *(const float4*)(src + (size_t)(hc * 64 + kk) * 256 + wno * 64 + c4);
        tile[kk][c4+0]=d.x; tile[kk][c4+1]=d.y; tile[kk][c4+2]=d.z; tile[kk][c4+3]=d.w;
    }
    __syncthreads();
    #pragma unroll
    for (int i = 0; i < 2; ++i) {
        int f = t + 256 * i;
        int ks2 = f >> 8;
        int r   = f & 255;
        int tq  = r >> 6;
        int r3  = r & 63;
        int l15v = r3 >> 2, gv = r3 & 3;
        int c_local = tq * 16 + l15v;
        int k_local = ks2 * 32 + gv * 8;
        unsigned short tmp[8];
        #pragma unroll
        for (int e = 0; e < 8; ++e) tmp[e] = f2bf(tile[k_local + e][c_local]);
        size_t off = (size_t)hc * 16384 + ((size_t)((wno * 2 + ks2) * 4 + tq)) * 512
                   + (gv * 16 + l15v) * 8;
        *(bf16x8*)(dst + off) = *(const bf16x8*)tmp;
    }
}

// ---------------------------------------------------------------------------
// Fused MLP v4: conflict-free frag reads + bF hoisted under GELU.
// ---------------------------------------------------------------------------
__global__ __launch_bounds__(512, 2) void mlp_fused(
    const float* __restrict__ xin, float* __restrict__ xio,
    const unsigned short* __restrict__ wt1, const float* __restrict__ b1,
    const unsigned short* __restrict__ wt2, const float* __restrict__ b2)
{
    __shared__ unsigned short w1c[2][16384];    // 32 KB per buf, frag-ordered
    __shared__ unsigned short w2c[2][16384];
    __shared__ unsigned short Hs[128][72];

    const int tid  = threadIdx.x;
    const int lane = tid & 63;
    const int l15  = lane & 15;
    const int g    = lane >> 4;
    const int wid  = tid >> 6;
    const int wmh  = wid >> 1, wnh = wid & 1;   // h-phase wave grid 4x2
    const int wmo  = wid >> 2, wno = wid & 3;   // out-phase wave grid 2x4
    const int fb   = (g * 16 + l15) * 8;        // frag offset: quarter-wave contiguous

    const size_t rowbase = (size_t)blockIdx.x * 128;

    auto stage = [&](const unsigned short* gbase, unsigned short* lbase) {
        #pragma unroll
        for (int i = 0; i < 4; ++i) {
            load_lds16(gbase + (i * 512 + tid) * 8,
                       lbase + (i * 512 + wid * 64) * 8);
        }
    };

    stage(wt1, &w1c[0][0]);
    stage(wt2, &w2c[0][0]);

    bf16x8 xf[2][8];
    #pragma unroll
    for (int mt = 0; mt < 2; ++mt) {
        const float* xr = xin + (rowbase + wmh * 32 + mt * 16 + l15) * 256;
        #pragma unroll
        for (int ks = 0; ks < 8; ++ks) {
            float4 a0 = *(const float4*)(xr + ks * 32 + g * 8);
            float4 a1 = *(const float4*)(xr + ks * 32 + g * 8 + 4);
            xf[mt][ks] = pack8(a0, a1);
        }
    }

    f32x4 oacc[4][4] = {};

    for (int hc = 0; hc < 16; ++hc) {
        const int cur = hc & 1;
        __syncthreads();   // drains chunk-hc DMA + orders Hs reuse

        if (hc < 15) {
            stage(wt1 + (size_t)(hc + 1) * 16384, &w1c[cur ^ 1][0]);
            stage(wt2 + (size_t)(hc + 1) * 16384, &w2c[cur ^ 1][0]);
        }

        // ---- h-phase: 128x64 = x @ w1c ----
        f32x4 hacc[2][2] = {};
        #pragma unroll
        for (int ks = 0; ks < 8; ++ks) {
            bf16x8 b0  = *(const bf16x8*)&w1c[cur][((wnh * 8 + ks) * 2 + 0) * 512 + fb];
            bf16x8 b1f = *(const bf16x8*)&w1c[cur][((wnh * 8 + ks) * 2 + 1) * 512 + fb];
            hacc[0][0] = mfma_bf16(xf[0][ks], b0,  hacc[0][0]);
            hacc[0][1] = mfma_bf16(xf[0][ks], b1f, hacc[0][1]);
            hacc[1][0] = mfma_bf16(xf[1][ks], b0,  hacc[1][0]);
            hacc[1][1] = mfma_bf16(xf[1][ks], b1f, hacc[1][1]);
        }

        // ---- hoist w2 frag reads: only depend on w2c[cur] (ready since top
        // barrier) — their LDS latency hides under the GELU VALU chain ----
        bf16x8 bF[2][4];
        #pragma unroll
        for (int ks2 = 0; ks2 < 2; ++ks2)
            #pragma unroll
            for (int t = 0; t < 4; ++t)
                bF[ks2][t] = *(const bf16x8*)&w2c[cur][((wno * 2 + ks2) * 4 + t) * 512 + fb];

        // ---- bias + GELU -> bf16 -> Hs ----
        #pragma unroll
        for (int nt = 0; nt < 2; ++nt) {
            int coll = wnh * 32 + nt * 16 + l15;
            float bias = b1[hc * 64 + coll];
            #pragma unroll
            for (int mt = 0; mt < 2; ++mt) {
                #pragma unroll
                for (int r = 0; r < 4; ++r) {
                    float vv = gelu_erf(hacc[mt][nt][r] + bias);
                    Hs[wmh * 32 + mt * 16 + g * 4 + r][coll] = f2bf(vv);
                }
            }
        }
        __syncthreads();

        // ---- out-phase: oacc += h(128x64) @ w2c(64x256) ----
        #pragma unroll
        for (int ks2 = 0; ks2 < 2; ++ks2) {
            bf16x8 aF[4];
            #pragma unroll
            for (int t = 0; t < 4; ++t)
                aF[t] = *(const bf16x8*)&Hs[wmo * 64 + t * 16 + l15][ks2 * 32 + g * 8];
            #pragma unroll
            for (int mt = 0; mt < 4; ++mt)
                #pragma unroll
                for (int nt = 0; nt < 4; ++nt)
                    oacc[mt][nt] = mfma_bf16(aF[mt], bF[ks2][nt], oacc[mt][nt]);
        }
    }

    #pragma unroll
    for (int nt = 0; nt < 4; ++nt) {
        int col = wno * 64 + nt * 16 + l15;
        float bias = b2[col];
        #pragma unroll
        for (int mt = 0; mt < 4; ++mt) {
            #pragma unroll
            for (int r = 0; r < 4; ++r) {
                size_t idx = (rowbase + wmo * 64 + mt * 16 + g * 4 + r) * 256 + col;
                xio[idx] = oacc[mt][nt][r] + bias + xio[idx];
            }
        }
    }
}

// ---------------------------------------------------------------------------
extern "C" void kernel_launch(void* const* d_in, const int* in_sizes, int n_in,
                              void* d_out, int out_size, void* d_ws, size_t ws_size,
                              hipStream_t stream)
{
    const float* q    = (const float*)d_in[0];
    const float* k    = (const float*)d_in[1];
    const float* v    = (const float*)d_in[2];
    const float* mask = (const float*)d_in[3];
    const float* w1   = (const float*)d_in[6];
    const float* b1   = (const float*)d_in[7];
    const float* w2   = (const float*)d_in[8];
    const float* b2   = (const float*)d_in[9];

    float* xio = (float*)d_out;

    unsigned short* wt1 = (unsigned short*)d_ws;                 // 16 chunks x 32 KB
    unsigned short* wt2 = wt1 + (size_t)1024 * 256;

    prep_w1<<<dim3(4, 16), 256, 0, stream>>>(w1, wt1);
    prep_w2<<<dim3(4, 16), 256, 0, stream>>>(w2, wt2);

    attn_kernel<<<8192, 256, 0, stream>>>(q, k, v, mask, xio);

    mlp_fused<<<512, 512, 0, stream>>>(xio, xio, wt1, b1, wt2, b2);
}